// Round 16
// baseline (229.543 us; speedup 1.0000x reference)
//
#include <hip/hip_runtime.h>

typedef short short8 __attribute__((ext_vector_type(8)));
typedef unsigned uint2v __attribute__((ext_vector_type(2)));
typedef float f32x4 __attribute__((ext_vector_type(4)));
typedef unsigned short u16;

#define MFMA16(a, b, c) __builtin_amdgcn_mfma_f32_16x16x32_bf16(a, b, c, 0, 0, 0)
#define GLD_LDS(g, l)                                                          \
  __builtin_amdgcn_global_load_lds(                                            \
      (__attribute__((address_space(1))) const void*)(const void*)(g),         \
      (__attribute__((address_space(3))) void*)(l), 16, 0, 0)

__device__ __forceinline__ u16 f2bf(float f) {
  union { float f; unsigned u; } x; x.f = f;
  unsigned r = x.u + 0x7fffu + ((x.u >> 16) & 1u);
  return (u16)(r >> 16);
}
__device__ __forceinline__ unsigned pk2(float a, float b) {
  return (unsigned)f2bf(a) | ((unsigned)f2bf(b) << 16);
}

// ---------------- kernel 0: prep ----------------
__global__ __launch_bounds__(256) void prep(const float* __restrict__ Wv,
                                            const float* __restrict__ Wk,
                                            const float* __restrict__ Wq,
                                            const float* __restrict__ Wo,
                                            u16* __restrict__ WoT2,
                                            u16* __restrict__ Mt) {
  __shared__ __align__(16) float A[64][65];
  __shared__ __align__(16) float B[64][68];
  const int t = threadIdx.x;
  const int r = t >> 2, c = (t & 3) * 16;
  if (blockIdx.x < 256) {
    const int tr = blockIdx.x >> 4, tc = blockIdx.x & 15;
#pragma unroll
    for (int u = 0; u < 4; ++u)
      *(float4*)&A[r][c + u * 4] = *(const float4*)(Wv + r * 64 + c + u * 4);
#pragma unroll
    for (int u = 0; u < 4; ++u)
      *(float4*)&B[r][c + u * 4] =
          *(const float4*)(Wo + (tr * 64 + r) * 1024 + tc * 64 + c + u * 4);
    __syncthreads();
    const int n = t & 63, i0 = (t >> 6) * 16;
    float acc[16];
#pragma unroll
    for (int ii = 0; ii < 16; ++ii) acc[ii] = 0.f;
    for (int j = 0; j < 64; ++j) {
      const float wo = B[j][n];
#pragma unroll
      for (int ii = 0; ii < 16; ++ii) acc[ii] += A[i0 + ii][j] * wo;
    }
    u16* dst = WoT2 + (size_t)(tc * 64 + n) * 1024 + tr * 64 + i0;
    short8 o0, o1;
#pragma unroll
    for (int jj = 0; jj < 8; ++jj) { o0[jj] = (short)f2bf(acc[jj]); o1[jj] = (short)f2bf(acc[8 + jj]); }
    *(short8*)(void*)dst = o0;
    *(short8*)(void*)(dst + 8) = o1;
  } else {
#pragma unroll
    for (int u = 0; u < 4; ++u)
      *(float4*)&A[r][c + u * 4] = *(const float4*)(Wq + r * 64 + c + u * 4);
#pragma unroll
    for (int u = 0; u < 4; ++u)
      *(float4*)&B[r][c + u * 4] = *(const float4*)(Wk + r * 64 + c + u * 4);
    __syncthreads();
    const int n = t & 63, k0 = (t >> 6) * 16;
    float acc[16];
#pragma unroll
    for (int ii = 0; ii < 16; ++ii) acc[ii] = 0.f;
    for (int d = 0; d < 64; ++d) {
      const float wk = B[n][d];
#pragma unroll
      for (int kk = 0; kk < 16; ++kk) acc[kk] += A[k0 + kk][d] * wk;
    }
    u16* dst = Mt + n * 64 + k0;
    short8 o0, o1;
#pragma unroll
    for (int jj = 0; jj < 8; ++jj) { o0[jj] = (short)f2bf(acc[jj]); o1[jj] = (short)f2bf(acc[8 + jj]); }
    *(short8*)(void*)dst = o0;
    *(short8*)(void*)(dst + 8) = o1;
  }
}

// ---------------- kernel 1: fused attention (frozen at R11/R13 best) ------
__global__ __launch_bounds__(256, 4) void attn_kernel(
    const float* __restrict__ values, const float* __restrict__ keys,
    const float* __restrict__ query, const int* __restrict__ mask,
    const u16* __restrict__ Mt, float* __restrict__ attn,
    u16* __restrict__ out2) {
  __shared__ __align__(16) u16 x1[4][16][68];
  __shared__ __align__(16) u16 x2[4][16][68];
  __shared__ __align__(16) u16 vTp[4][64][24];

  const int tid = threadIdx.x;
  const int w = tid >> 6, lane = tid & 63;
  const int g16 = lane & 15;
  const int q4 = lane >> 4;
  const int kbase = q4 * 8;
  const int mrow = q4 * 4;
  const int pg16 = (g16 & 3) * 4 + (g16 >> 2);

  u16 (*mt)[68] = (u16(*)[68]) & x1[0][0][0];
  {
    const short8* mg = (const short8*)Mt;
    short8 a0 = mg[tid];
    short8 a1 = mg[256 + tid];
    *(short8*)&mt[tid >> 3][(tid & 7) * 8] = a0;
    const int g1 = 256 + tid;
    *(short8*)&mt[g1 >> 3][(g1 & 7) * 8] = a1;
  }
  __syncthreads();
  short8 mtf[2][4];
#pragma unroll
  for (int kb = 0; kb < 2; ++kb)
#pragma unroll
    for (int nc = 0; nc < 4; ++nc)
      mtf[kb][nc] = *(const short8*)&mt[nc * 16 + g16][kb * 32 + kbase];
  __syncthreads();

  int mzb = 0;
#pragma unroll
  for (int r = 0; r < 4; ++r)
    mzb |= (mask[(mrow + r) * 16 + g16] == 0) ? (1 << r) : 0;

  const f32x4 zero = {0.f, 0.f, 0.f, 0.f};
  const int pbase = blockIdx.x * 16 + w * 4;

  const f32x4* qv = (const f32x4*)query;
  const f32x4* kv = (const f32x4*)keys;
  const f32x4* vv = (const f32x4*)values;
  const size_t b0 = (size_t)pbase * 256 + lane;

  f32x4 qf0 = qv[b0], qf1 = qv[b0 + 64], qf2 = qv[b0 + 128], qf3 = qv[b0 + 192];
  f32x4 kf0 = kv[b0], kf1 = kv[b0 + 64], kf2 = kv[b0 + 128], kf3 = kv[b0 + 192];
  f32x4 vf0 = vv[b0], vf1 = vv[b0 + 64], vf2 = vv[b0 + 128], vf3 = vv[b0 + 192];

  const int wr = lane >> 4;
  const int wc = (lane & 15) * 4;

#pragma unroll
  for (int i = 0; i < 4; ++i) {
    const int p = pbase + i;

    *(uint2v*)&x1[w][0 + wr][wc] = uint2v{pk2(qf0[0], qf0[1]), pk2(qf0[2], qf0[3])};
    *(uint2v*)&x1[w][4 + wr][wc] = uint2v{pk2(qf1[0], qf1[1]), pk2(qf1[2], qf1[3])};
    *(uint2v*)&x1[w][8 + wr][wc] = uint2v{pk2(qf2[0], qf2[1]), pk2(qf2[2], qf2[3])};
    *(uint2v*)&x1[w][12 + wr][wc] = uint2v{pk2(qf3[0], qf3[1]), pk2(qf3[2], qf3[3])};
    *(uint2v*)&x2[w][0 + wr][wc] = uint2v{pk2(kf0[0], kf0[1]), pk2(kf0[2], kf0[3])};
    *(uint2v*)&x2[w][4 + wr][wc] = uint2v{pk2(kf1[0], kf1[1]), pk2(kf1[2], kf1[3])};
    *(uint2v*)&x2[w][8 + wr][wc] = uint2v{pk2(kf2[0], kf2[1]), pk2(kf2[2], kf2[3])};
    *(uint2v*)&x2[w][12 + wr][wc] = uint2v{pk2(kf3[0], kf3[1]), pk2(kf3[2], kf3[3])};
#pragma unroll
    for (int j = 0; j < 4; ++j) {
      uint2v col;
      col[0] = pk2(vf0[j], vf1[j]);
      col[1] = pk2(vf2[j], vf3[j]);
      *(uint2v*)&vTp[w][wc + j][wr * 4] = col;
    }

    if (i < 3) {
      const size_t nb = b0 + (size_t)(i + 1) * 256;
      qf0 = qv[nb]; qf1 = qv[nb + 64]; qf2 = qv[nb + 128]; qf3 = qv[nb + 192];
      kf0 = kv[nb]; kf1 = kv[nb + 64]; kf2 = kv[nb + 128]; kf3 = kv[nb + 192];
      vf0 = vv[nb]; vf1 = vv[nb + 64]; vf2 = vv[nb + 128]; vf3 = vv[nb + 192];
    }
    __builtin_amdgcn_sched_barrier(0);

    short8 aq0 = *(const short8*)&x1[w][g16][kbase];
    short8 aq1 = *(const short8*)&x1[w][g16][32 + kbase];
    short8 ak0 = *(const short8*)&x2[w][g16][kbase];
    short8 ak1 = *(const short8*)&x2[w][g16][32 + kbase];

    f32x4 tacc[4];
#pragma unroll
    for (int nc = 0; nc < 4; ++nc) {
      tacc[nc] = MFMA16(aq0, mtf[0][nc], zero);
      tacc[nc] = MFMA16(aq1, mtf[1][nc], tacc[nc]);
    }
#pragma unroll
    for (int nc = 0; nc < 4; ++nc)
#pragma unroll
      for (int r = 0; r < 4; ++r)
        x1[w][mrow + r][nc * 16 + g16] = f2bf(tacc[nc][r]);

    short8 ea0 = *(const short8*)&x1[w][g16][kbase];
    short8 ea1 = *(const short8*)&x1[w][g16][32 + kbase];
    f32x4 acce = MFMA16(ea0, ak0, zero);
    acce = MFMA16(ea1, ak1, acce);

    const float SC = 0.045084220027780106f;
    float* ap = attn + (size_t)p * 256 + mrow * 16 + g16;
#pragma unroll
    for (int r = 0; r < 4; ++r) {
      const float val = ((mzb >> r) & 1) ? -45.f : acce[r] * SC;
      const float pe = exp2f(val);
      float s = pe;
      s += __shfl_xor(s, 1, 16);
      s += __shfl_xor(s, 2, 16);
      s += __shfl_xor(s, 4, 16);
      s += __shfl_xor(s, 8, 16);
      const float a = pe * __builtin_amdgcn_rcpf(s);
      ap[r * 16] = a;
      x2[w][mrow + r][pg16] = f2bf(a);
    }

    short8 pa;
    if (lane < 32) {
      pa = *(const short8*)&x2[w][g16][kbase];
    } else {
      short8 z = {0, 0, 0, 0, 0, 0, 0, 0};
      pa = z;
    }
    const int gsel = (lane < 32) ? kbase : 0;
#pragma unroll
    for (int nc = 0; nc < 4; ++nc) {
      short8 vb = *(const short8*)&vTp[w][nc * 16 + g16][gsel];
      f32x4 acco = MFMA16(pa, vb, zero);
#pragma unroll
      for (int r = 0; r < 4; ++r)
        x1[w][mrow + r][nc * 16 + g16] = f2bf(acco[r]);
    }

    {
      short8 s0 = *(const short8*)&x1[w][lane >> 3][(lane & 7) * 8];
      short8 s1 = *(const short8*)&x1[w][8 + (lane >> 3)][(lane & 7) * 8];
      u16* dst = out2 + (size_t)p * 1024 + lane * 8;
      *(short8*)(void*)dst = s0;
      *(short8*)(void*)(dst + 512) = s1;
    }
  }
}

// ---------------- kernel 2: deep-pipelined GEMM v3: XCD-grouped bm --------
// Same ring/swizzle/counted-vmcnt schedule as R14. NEW: bijective blockIdx
// remap so the 4 bn-blocks sharing a bm (same 256KB A-panel) dispatch
// consecutively on the SAME XCD -> A served from that XCD's L2 for 3 of 4
// readers, cutting delivered A-traffic ~4x (gemm is delivered-BW-bound).
__global__ __launch_bounds__(512, 2) void gemm8_kernel(
    const u16* __restrict__ A, const u16* __restrict__ BT,
    const float* __restrict__ bo, float* __restrict__ C) {
  __shared__ __align__(16) u16 As[3][128 * 64];  // 48 KB
  __shared__ __align__(16) u16 Bs[3][256 * 64];  // 96 KB
  const int tid = threadIdx.x;
  const int lane = tid & 63;
  const int w = tid >> 6;
  const int wm = w >> 2, wn = w & 3;
  const int g16 = lane & 15, q4 = lane >> 4;
  // XCD-grouped remap (bijective: 1024 = 8 XCDs x 128 slots):
  //   xcd = l&7 owns bm in [xcd*32, xcd*32+32); slot>>2 = bm offset, slot&3 = bn
  const int l = blockIdx.x;
  const int xcd = l & 7, slot = l >> 3;
  const int bm = xcd * 32 + (slot >> 2), bn = slot & 3;

  const int r0 = tid >> 3, sl = tid & 7;
  const int r1 = r0 + 64;
  const int sw0 = sl ^ (r0 & 7);
  const int sw1 = sl ^ (r1 & 7);
  const int R0 = bm * 128 + r0, R1 = bm * 128 + r1;
  const size_t a_src0 =
      ((size_t)((R0 >> 12) * 4096 + (R0 & 255) * 16)) * 1024 +
      ((R0 & 4095) >> 8) * 64 + sw0 * 8;
  const size_t a_src1 =
      ((size_t)((R1 >> 12) * 4096 + (R1 & 255) * 16)) * 1024 +
      ((R1 & 4095) >> 8) * 64 + sw1 * 8;
  const size_t b_src00 = (size_t)(bn * 256 + r0) * 1024 + sw0 * 8;
  const size_t b_src01 = (size_t)(bn * 256 + r1) * 1024 + sw1 * 8;
  const size_t b_src10 = (size_t)(bn * 256 + 128 + r0) * 1024 + sw0 * 8;
  const size_t b_src11 = (size_t)(bn * 256 + 128 + r1) * 1024 + sw1 * 8;

#define SA(kt, s)                                                              \
  {                                                                            \
    GLD_LDS(A + a_src0 + (kt) * 1024, &As[s][tid * 8]);                        \
    GLD_LDS(A + a_src1 + (kt) * 1024, &As[s][tid * 8 + 4096]);                 \
  }
#define SB0(kt, s)                                                             \
  {                                                                            \
    GLD_LDS(BT + b_src00 + (kt) * 64, &Bs[s][tid * 8]);                        \
    GLD_LDS(BT + b_src01 + (kt) * 64, &Bs[s][tid * 8 + 4096]);                 \
  }
#define SB1(kt, s)                                                             \
  {                                                                            \
    GLD_LDS(BT + b_src10 + (kt) * 64, &Bs[s][8192 + tid * 8]);                 \
    GLD_LDS(BT + b_src11 + (kt) * 64, &Bs[s][8192 + tid * 8 + 4096]);          \
  }

  f32x4 acc[4][4];
  const f32x4 zero = {0.f, 0.f, 0.f, 0.f};
#pragma unroll
  for (int m = 0; m < 4; ++m)
#pragma unroll
    for (int n = 0; n < 4; ++n) acc[m][n] = zero;

  SA(0, 0); SB0(0, 0); SB1(0, 0);
  SA(1, 1); SB0(1, 1); SB1(1, 1);
  asm volatile("s_waitcnt vmcnt(6)" ::: "memory");
  __builtin_amdgcn_sched_barrier(0);
  __builtin_amdgcn_s_barrier();

  const int swz = g16 & 7;
  int rs = 0;
#pragma unroll 1
  for (int t = 0; t < 16; ++t) {
    const int ss = (rs == 0) ? 2 : rs - 1;  // (t+2)%3
    const u16* Ar = &As[rs][0];
    const u16* Br = &Bs[rs][0];

    short8 af[4][2], bf[4][2];
#pragma unroll
    for (int m = 0; m < 4; ++m)
#pragma unroll
      for (int ks = 0; ks < 2; ++ks)
        af[m][ks] = *(const short8*)&Ar[(wm * 64 + m * 16 + g16) * 64 +
                                        (((ks << 2) + q4) ^ swz) * 8];
#pragma unroll
    for (int n = 0; n < 2; ++n)
#pragma unroll
      for (int ks = 0; ks < 2; ++ks)
        bf[n][ks] = *(const short8*)&Br[(wn * 64 + n * 16 + g16) * 64 +
                                        (((ks << 2) + q4) ^ swz) * 8];
    if (t < 14) { SA(t + 2, ss); SB0(t + 2, ss); }
    __builtin_amdgcn_s_setprio(1);
#pragma unroll
    for (int m = 0; m < 4; ++m)
#pragma unroll
      for (int n = 0; n < 2; ++n) {
        acc[m][n] = MFMA16(af[m][0], bf[n][0], acc[m][n]);
        acc[m][n] = MFMA16(af[m][1], bf[n][1], acc[m][n]);
      }
    __builtin_amdgcn_s_setprio(0);

#pragma unroll
    for (int n = 2; n < 4; ++n)
#pragma unroll
      for (int ks = 0; ks < 2; ++ks)
        bf[n][ks] = *(const short8*)&Br[(wn * 64 + n * 16 + g16) * 64 +
                                        (((ks << 2) + q4) ^ swz) * 8];
    if (t < 14) SB1(t + 2, ss);
    __builtin_amdgcn_s_setprio(1);
#pragma unroll
    for (int m = 0; m < 4; ++m)
#pragma unroll
      for (int n = 2; n < 4; ++n) {
        acc[m][n] = MFMA16(af[m][0], bf[n][0], acc[m][n]);
        acc[m][n] = MFMA16(af[m][1], bf[n][1], acc[m][n]);
      }
    __builtin_amdgcn_s_setprio(0);

    if (t == 14) {
      asm volatile("s_waitcnt vmcnt(0)" ::: "memory");
    } else {
      asm volatile("s_waitcnt vmcnt(6)" ::: "memory");
    }
    __builtin_amdgcn_sched_barrier(0);
    __builtin_amdgcn_s_barrier();
    rs = (rs == 2) ? 0 : rs + 1;
  }
#undef SA
#undef SB0
#undef SB1

#pragma unroll
  for (int n = 0; n < 4; ++n) {
    const int col = bn * 256 + wn * 64 + n * 16 + g16;
    const float bias = bo[col];
#pragma unroll
    for (int m = 0; m < 4; ++m) {
#pragma unroll
      for (int r = 0; r < 4; ++r) {
        const int row = bm * 128 + wm * 64 + m * 16 + q4 * 4 + r;
        C[(size_t)row * 1024 + col] = acc[m][n][r] + bias;
      }
    }
  }
}

extern "C" void kernel_launch(void* const* d_in, const int* in_sizes, int n_in,
                              void* d_out, int out_size, void* d_ws,
                              size_t ws_size, hipStream_t stream) {
  const float* values = (const float*)d_in[0];
  const float* keys   = (const float*)d_in[1];
  const float* query  = (const float*)d_in[2];
  const int*   mask   = (const int*)d_in[3];
  const float* Wv = (const float*)d_in[4];
  const float* Wk = (const float*)d_in[5];
  const float* Wq = (const float*)d_in[6];
  const float* Wo = (const float*)d_in[7];
  const float* bo = (const float*)d_in[8];

  float* out  = (float*)d_out;        // 8*4096*1024 fp32
  float* attn = out + 33554432;       // 8*4096*16*16 fp32

  u16* out2 = (u16*)d_ws;             // 32768 x 1024 bf16, natural layout
  u16* WoT2 = out2 + 33554432;        // 1024 x 1024 bf16
  u16* Mt   = WoT2 + 1048576;         // 64 x 64 bf16

  prep<<<257, 256, 0, stream>>>(Wv, Wk, Wq, Wo, WoT2, Mt);
  attn_kernel<<<2048, 256, 0, stream>>>(values, keys, query, mask, Mt, attn,
                                        out2);
  gemm8_kernel<<<1024, 512, 0, stream>>>(out2, WoT2, bo, out);
}

// Round 17
// 222.528 us; speedup vs baseline: 1.0315x; 1.0315x over previous
//
#include <hip/hip_runtime.h>

typedef short short8 __attribute__((ext_vector_type(8)));
typedef unsigned uint2v __attribute__((ext_vector_type(2)));
typedef float f32x4 __attribute__((ext_vector_type(4)));
typedef unsigned short u16;

#define MFMA16(a, b, c) __builtin_amdgcn_mfma_f32_16x16x32_bf16(a, b, c, 0, 0, 0)
#define GLD_LDS(g, l)                                                          \
  __builtin_amdgcn_global_load_lds(                                            \
      (__attribute__((address_space(1))) const void*)(const void*)(g),         \
      (__attribute__((address_space(3))) void*)(l), 16, 0, 0)

__device__ __forceinline__ u16 f2bf(float f) {
  union { float f; unsigned u; } x; x.f = f;
  unsigned r = x.u + 0x7fffu + ((x.u >> 16) & 1u);
  return (u16)(r >> 16);
}
__device__ __forceinline__ unsigned pk2(float a, float b) {
  return (unsigned)f2bf(a) | ((unsigned)f2bf(b) << 16);
}

// ---------------- kernel 0: prep ----------------
__global__ __launch_bounds__(256) void prep(const float* __restrict__ Wv,
                                            const float* __restrict__ Wk,
                                            const float* __restrict__ Wq,
                                            const float* __restrict__ Wo,
                                            u16* __restrict__ WoT2,
                                            u16* __restrict__ Mt) {
  __shared__ __align__(16) float A[64][65];
  __shared__ __align__(16) float B[64][68];
  const int t = threadIdx.x;
  const int r = t >> 2, c = (t & 3) * 16;
  if (blockIdx.x < 256) {
    const int tr = blockIdx.x >> 4, tc = blockIdx.x & 15;
#pragma unroll
    for (int u = 0; u < 4; ++u)
      *(float4*)&A[r][c + u * 4] = *(const float4*)(Wv + r * 64 + c + u * 4);
#pragma unroll
    for (int u = 0; u < 4; ++u)
      *(float4*)&B[r][c + u * 4] =
          *(const float4*)(Wo + (tr * 64 + r) * 1024 + tc * 64 + c + u * 4);
    __syncthreads();
    const int n = t & 63, i0 = (t >> 6) * 16;
    float acc[16];
#pragma unroll
    for (int ii = 0; ii < 16; ++ii) acc[ii] = 0.f;
    for (int j = 0; j < 64; ++j) {
      const float wo = B[j][n];
#pragma unroll
      for (int ii = 0; ii < 16; ++ii) acc[ii] += A[i0 + ii][j] * wo;
    }
    u16* dst = WoT2 + (size_t)(tc * 64 + n) * 1024 + tr * 64 + i0;
    short8 o0, o1;
#pragma unroll
    for (int jj = 0; jj < 8; ++jj) { o0[jj] = (short)f2bf(acc[jj]); o1[jj] = (short)f2bf(acc[8 + jj]); }
    *(short8*)(void*)dst = o0;
    *(short8*)(void*)(dst + 8) = o1;
  } else {
#pragma unroll
    for (int u = 0; u < 4; ++u)
      *(float4*)&A[r][c + u * 4] = *(const float4*)(Wq + r * 64 + c + u * 4);
#pragma unroll
    for (int u = 0; u < 4; ++u)
      *(float4*)&B[r][c + u * 4] = *(const float4*)(Wk + r * 64 + c + u * 4);
    __syncthreads();
    const int n = t & 63, k0 = (t >> 6) * 16;
    float acc[16];
#pragma unroll
    for (int ii = 0; ii < 16; ++ii) acc[ii] = 0.f;
    for (int d = 0; d < 64; ++d) {
      const float wk = B[n][d];
#pragma unroll
      for (int kk = 0; kk < 16; ++kk) acc[kk] += A[k0 + kk][d] * wk;
    }
    u16* dst = Mt + n * 64 + k0;
    short8 o0, o1;
#pragma unroll
    for (int jj = 0; jj < 8; ++jj) { o0[jj] = (short)f2bf(acc[jj]); o1[jj] = (short)f2bf(acc[8 + jj]); }
    *(short8*)(void*)dst = o0;
    *(short8*)(void*)(dst + 8) = o1;
  }
}

// ---------------- kernel 1: fused attention (frozen at R11/R13 best) ------
__global__ __launch_bounds__(256, 4) void attn_kernel(
    const float* __restrict__ values, const float* __restrict__ keys,
    const float* __restrict__ query, const int* __restrict__ mask,
    const u16* __restrict__ Mt, float* __restrict__ attn,
    u16* __restrict__ out2) {
  __shared__ __align__(16) u16 x1[4][16][68];
  __shared__ __align__(16) u16 x2[4][16][68];
  __shared__ __align__(16) u16 vTp[4][64][24];

  const int tid = threadIdx.x;
  const int w = tid >> 6, lane = tid & 63;
  const int g16 = lane & 15;
  const int q4 = lane >> 4;
  const int kbase = q4 * 8;
  const int mrow = q4 * 4;
  const int pg16 = (g16 & 3) * 4 + (g16 >> 2);

  u16 (*mt)[68] = (u16(*)[68]) & x1[0][0][0];
  {
    const short8* mg = (const short8*)Mt;
    short8 a0 = mg[tid];
    short8 a1 = mg[256 + tid];
    *(short8*)&mt[tid >> 3][(tid & 7) * 8] = a0;
    const int g1 = 256 + tid;
    *(short8*)&mt[g1 >> 3][(g1 & 7) * 8] = a1;
  }
  __syncthreads();
  short8 mtf[2][4];
#pragma unroll
  for (int kb = 0; kb < 2; ++kb)
#pragma unroll
    for (int nc = 0; nc < 4; ++nc)
      mtf[kb][nc] = *(const short8*)&mt[nc * 16 + g16][kb * 32 + kbase];
  __syncthreads();

  int mzb = 0;
#pragma unroll
  for (int r = 0; r < 4; ++r)
    mzb |= (mask[(mrow + r) * 16 + g16] == 0) ? (1 << r) : 0;

  const f32x4 zero = {0.f, 0.f, 0.f, 0.f};
  const int pbase = blockIdx.x * 16 + w * 4;

  const f32x4* qv = (const f32x4*)query;
  const f32x4* kv = (const f32x4*)keys;
  const f32x4* vv = (const f32x4*)values;
  const size_t b0 = (size_t)pbase * 256 + lane;

  f32x4 qf0 = qv[b0], qf1 = qv[b0 + 64], qf2 = qv[b0 + 128], qf3 = qv[b0 + 192];
  f32x4 kf0 = kv[b0], kf1 = kv[b0 + 64], kf2 = kv[b0 + 128], kf3 = kv[b0 + 192];
  f32x4 vf0 = vv[b0], vf1 = vv[b0 + 64], vf2 = vv[b0 + 128], vf3 = vv[b0 + 192];

  const int wr = lane >> 4;
  const int wc = (lane & 15) * 4;

#pragma unroll
  for (int i = 0; i < 4; ++i) {
    const int p = pbase + i;

    *(uint2v*)&x1[w][0 + wr][wc] = uint2v{pk2(qf0[0], qf0[1]), pk2(qf0[2], qf0[3])};
    *(uint2v*)&x1[w][4 + wr][wc] = uint2v{pk2(qf1[0], qf1[1]), pk2(qf1[2], qf1[3])};
    *(uint2v*)&x1[w][8 + wr][wc] = uint2v{pk2(qf2[0], qf2[1]), pk2(qf2[2], qf2[3])};
    *(uint2v*)&x1[w][12 + wr][wc] = uint2v{pk2(qf3[0], qf3[1]), pk2(qf3[2], qf3[3])};
    *(uint2v*)&x2[w][0 + wr][wc] = uint2v{pk2(kf0[0], kf0[1]), pk2(kf0[2], kf0[3])};
    *(uint2v*)&x2[w][4 + wr][wc] = uint2v{pk2(kf1[0], kf1[1]), pk2(kf1[2], kf1[3])};
    *(uint2v*)&x2[w][8 + wr][wc] = uint2v{pk2(kf2[0], kf2[1]), pk2(kf2[2], kf2[3])};
    *(uint2v*)&x2[w][12 + wr][wc] = uint2v{pk2(kf3[0], kf3[1]), pk2(kf3[2], kf3[3])};
#pragma unroll
    for (int j = 0; j < 4; ++j) {
      uint2v col;
      col[0] = pk2(vf0[j], vf1[j]);
      col[1] = pk2(vf2[j], vf3[j]);
      *(uint2v*)&vTp[w][wc + j][wr * 4] = col;
    }

    if (i < 3) {
      const size_t nb = b0 + (size_t)(i + 1) * 256;
      qf0 = qv[nb]; qf1 = qv[nb + 64]; qf2 = qv[nb + 128]; qf3 = qv[nb + 192];
      kf0 = kv[nb]; kf1 = kv[nb + 64]; kf2 = kv[nb + 128]; kf3 = kv[nb + 192];
      vf0 = vv[nb]; vf1 = vv[nb + 64]; vf2 = vv[nb + 128]; vf3 = vv[nb + 192];
    }
    __builtin_amdgcn_sched_barrier(0);

    short8 aq0 = *(const short8*)&x1[w][g16][kbase];
    short8 aq1 = *(const short8*)&x1[w][g16][32 + kbase];
    short8 ak0 = *(const short8*)&x2[w][g16][kbase];
    short8 ak1 = *(const short8*)&x2[w][g16][32 + kbase];

    f32x4 tacc[4];
#pragma unroll
    for (int nc = 0; nc < 4; ++nc) {
      tacc[nc] = MFMA16(aq0, mtf[0][nc], zero);
      tacc[nc] = MFMA16(aq1, mtf[1][nc], tacc[nc]);
    }
#pragma unroll
    for (int nc = 0; nc < 4; ++nc)
#pragma unroll
      for (int r = 0; r < 4; ++r)
        x1[w][mrow + r][nc * 16 + g16] = f2bf(tacc[nc][r]);

    short8 ea0 = *(const short8*)&x1[w][g16][kbase];
    short8 ea1 = *(const short8*)&x1[w][g16][32 + kbase];
    f32x4 acce = MFMA16(ea0, ak0, zero);
    acce = MFMA16(ea1, ak1, acce);

    const float SC = 0.045084220027780106f;
    float* ap = attn + (size_t)p * 256 + mrow * 16 + g16;
#pragma unroll
    for (int r = 0; r < 4; ++r) {
      const float val = ((mzb >> r) & 1) ? -45.f : acce[r] * SC;
      const float pe = exp2f(val);
      float s = pe;
      s += __shfl_xor(s, 1, 16);
      s += __shfl_xor(s, 2, 16);
      s += __shfl_xor(s, 4, 16);
      s += __shfl_xor(s, 8, 16);
      const float a = pe * __builtin_amdgcn_rcpf(s);
      ap[r * 16] = a;
      x2[w][mrow + r][pg16] = f2bf(a);
    }

    short8 pa;
    if (lane < 32) {
      pa = *(const short8*)&x2[w][g16][kbase];
    } else {
      short8 z = {0, 0, 0, 0, 0, 0, 0, 0};
      pa = z;
    }
    const int gsel = (lane < 32) ? kbase : 0;
#pragma unroll
    for (int nc = 0; nc < 4; ++nc) {
      short8 vb = *(const short8*)&vTp[w][nc * 16 + g16][gsel];
      f32x4 acco = MFMA16(pa, vb, zero);
#pragma unroll
      for (int r = 0; r < 4; ++r)
        x1[w][mrow + r][nc * 16 + g16] = f2bf(acco[r]);
    }

    {
      short8 s0 = *(const short8*)&x1[w][lane >> 3][(lane & 7) * 8];
      short8 s1 = *(const short8*)&x1[w][8 + (lane >> 3)][(lane & 7) * 8];
      u16* dst = out2 + (size_t)p * 1024 + lane * 8;
      *(short8*)(void*)dst = s0;
      *(short8*)(void*)(dst + 512) = s1;
    }
  }
}

// ---------------- kernel 2: deep-pipelined GEMM v2 (R14 best: linear map) -
// 3-slot ring, counted vmcnt(6), one barrier/tile, T2 swizzle, setprio.
// R15's XCD-grouped remap REVERTED (measured neutral-to-negative).
__global__ __launch_bounds__(512, 2) void gemm8_kernel(
    const u16* __restrict__ A, const u16* __restrict__ BT,
    const float* __restrict__ bo, float* __restrict__ C) {
  __shared__ __align__(16) u16 As[3][128 * 64];  // 48 KB
  __shared__ __align__(16) u16 Bs[3][256 * 64];  // 96 KB
  const int tid = threadIdx.x;
  const int lane = tid & 63;
  const int w = tid >> 6;
  const int wm = w >> 2, wn = w & 3;
  const int g16 = lane & 15, q4 = lane >> 4;
  const int bm = blockIdx.x >> 2, bn = blockIdx.x & 3;

  const int r0 = tid >> 3, sl = tid & 7;
  const int r1 = r0 + 64;
  const int sw0 = sl ^ (r0 & 7);
  const int sw1 = sl ^ (r1 & 7);
  const int R0 = bm * 128 + r0, R1 = bm * 128 + r1;
  const size_t a_src0 =
      ((size_t)((R0 >> 12) * 4096 + (R0 & 255) * 16)) * 1024 +
      ((R0 & 4095) >> 8) * 64 + sw0 * 8;
  const size_t a_src1 =
      ((size_t)((R1 >> 12) * 4096 + (R1 & 255) * 16)) * 1024 +
      ((R1 & 4095) >> 8) * 64 + sw1 * 8;
  const size_t b_src00 = (size_t)(bn * 256 + r0) * 1024 + sw0 * 8;
  const size_t b_src01 = (size_t)(bn * 256 + r1) * 1024 + sw1 * 8;
  const size_t b_src10 = (size_t)(bn * 256 + 128 + r0) * 1024 + sw0 * 8;
  const size_t b_src11 = (size_t)(bn * 256 + 128 + r1) * 1024 + sw1 * 8;

#define SA(kt, s)                                                              \
  {                                                                            \
    GLD_LDS(A + a_src0 + (kt) * 1024, &As[s][tid * 8]);                        \
    GLD_LDS(A + a_src1 + (kt) * 1024, &As[s][tid * 8 + 4096]);                 \
  }
#define SB0(kt, s)                                                             \
  {                                                                            \
    GLD_LDS(BT + b_src00 + (kt) * 64, &Bs[s][tid * 8]);                        \
    GLD_LDS(BT + b_src01 + (kt) * 64, &Bs[s][tid * 8 + 4096]);                 \
  }
#define SB1(kt, s)                                                             \
  {                                                                            \
    GLD_LDS(BT + b_src10 + (kt) * 64, &Bs[s][8192 + tid * 8]);                 \
    GLD_LDS(BT + b_src11 + (kt) * 64, &Bs[s][8192 + tid * 8 + 4096]);          \
  }

  f32x4 acc[4][4];
  const f32x4 zero = {0.f, 0.f, 0.f, 0.f};
#pragma unroll
  for (int m = 0; m < 4; ++m)
#pragma unroll
    for (int n = 0; n < 4; ++n) acc[m][n] = zero;

  SA(0, 0); SB0(0, 0); SB1(0, 0);
  SA(1, 1); SB0(1, 1); SB1(1, 1);
  asm volatile("s_waitcnt vmcnt(6)" ::: "memory");
  __builtin_amdgcn_sched_barrier(0);
  __builtin_amdgcn_s_barrier();

  const int swz = g16 & 7;
  int rs = 0;
#pragma unroll 1
  for (int t = 0; t < 16; ++t) {
    const int ss = (rs == 0) ? 2 : rs - 1;  // (t+2)%3
    const u16* Ar = &As[rs][0];
    const u16* Br = &Bs[rs][0];

    short8 af[4][2], bf[4][2];
#pragma unroll
    for (int m = 0; m < 4; ++m)
#pragma unroll
      for (int ks = 0; ks < 2; ++ks)
        af[m][ks] = *(const short8*)&Ar[(wm * 64 + m * 16 + g16) * 64 +
                                        (((ks << 2) + q4) ^ swz) * 8];
#pragma unroll
    for (int n = 0; n < 2; ++n)
#pragma unroll
      for (int ks = 0; ks < 2; ++ks)
        bf[n][ks] = *(const short8*)&Br[(wn * 64 + n * 16 + g16) * 64 +
                                        (((ks << 2) + q4) ^ swz) * 8];
    if (t < 14) { SA(t + 2, ss); SB0(t + 2, ss); }
    __builtin_amdgcn_s_setprio(1);
#pragma unroll
    for (int m = 0; m < 4; ++m)
#pragma unroll
      for (int n = 0; n < 2; ++n) {
        acc[m][n] = MFMA16(af[m][0], bf[n][0], acc[m][n]);
        acc[m][n] = MFMA16(af[m][1], bf[n][1], acc[m][n]);
      }
    __builtin_amdgcn_s_setprio(0);

#pragma unroll
    for (int n = 2; n < 4; ++n)
#pragma unroll
      for (int ks = 0; ks < 2; ++ks)
        bf[n][ks] = *(const short8*)&Br[(wn * 64 + n * 16 + g16) * 64 +
                                        (((ks << 2) + q4) ^ swz) * 8];
    if (t < 14) SB1(t + 2, ss);
    __builtin_amdgcn_s_setprio(1);
#pragma unroll
    for (int m = 0; m < 4; ++m)
#pragma unroll
      for (int n = 2; n < 4; ++n) {
        acc[m][n] = MFMA16(af[m][0], bf[n][0], acc[m][n]);
        acc[m][n] = MFMA16(af[m][1], bf[n][1], acc[m][n]);
      }
    __builtin_amdgcn_s_setprio(0);

    if (t == 14) {
      asm volatile("s_waitcnt vmcnt(0)" ::: "memory");
    } else {
      asm volatile("s_waitcnt vmcnt(6)" ::: "memory");
    }
    __builtin_amdgcn_sched_barrier(0);
    __builtin_amdgcn_s_barrier();
    rs = (rs == 2) ? 0 : rs + 1;
  }
#undef SA
#undef SB0
#undef SB1

#pragma unroll
  for (int n = 0; n < 4; ++n) {
    const int col = bn * 256 + wn * 64 + n * 16 + g16;
    const float bias = bo[col];
#pragma unroll
    for (int m = 0; m < 4; ++m) {
#pragma unroll
      for (int r = 0; r < 4; ++r) {
        const int row = bm * 128 + wm * 64 + m * 16 + q4 * 4 + r;
        C[(size_t)row * 1024 + col] = acc[m][n][r] + bias;
      }
    }
  }
}

extern "C" void kernel_launch(void* const* d_in, const int* in_sizes, int n_in,
                              void* d_out, int out_size, void* d_ws,
                              size_t ws_size, hipStream_t stream) {
  const float* values = (const float*)d_in[0];
  const float* keys   = (const float*)d_in[1];
  const float* query  = (const float*)d_in[2];
  const int*   mask   = (const int*)d_in[3];
  const float* Wv = (const float*)d_in[4];
  const float* Wk = (const float*)d_in[5];
  const float* Wq = (const float*)d_in[6];
  const float* Wo = (const float*)d_in[7];
  const float* bo = (const float*)d_in[8];

  float* out  = (float*)d_out;        // 8*4096*1024 fp32
  float* attn = out + 33554432;       // 8*4096*16*16 fp32

  u16* out2 = (u16*)d_ws;             // 32768 x 1024 bf16, natural layout
  u16* WoT2 = out2 + 33554432;        // 1024 x 1024 bf16
  u16* Mt   = WoT2 + 1048576;         // 64 x 64 bf16

  prep<<<257, 256, 0, stream>>>(Wv, Wk, Wq, Wo, WoT2, Mt);
  attn_kernel<<<2048, 256, 0, stream>>>(values, keys, query, mask, Mt, attn,
                                        out2);
  gemm8_kernel<<<1024, 512, 0, stream>>>(out2, WoT2, bo, out);
}